// Round 1
// baseline (1017.656 us; speedup 1.0000x reference)
//
#include <hip/hip_runtime.h>
#include <cmath>

namespace {

constexpr int Bb = 16, Nn_ = 64, FE = 1216, FN = 1108, MD = 256, KC = 600;
constexpr int PAIRS = Bb * Nn_ * Nn_;   // 65536
constexpr int ROWS  = Bb * Nn_;         // 1024

// workspace offsets (in floats)
constexpr size_t OFF_XP   = 0;                               // [1024][256]
constexpr size_t OFF_XPH  = OFF_XP   + (size_t)ROWS * MD;    // [1024][256]
constexpr size_t OFF_E0   = OFF_XPH  + (size_t)ROWS * MD;    // [65536][256]
constexpr size_t OFF_MPRE = OFF_E0   + (size_t)PAIRS * MD;   // [65536][256]
constexpr size_t OFF_S1   = OFF_MPRE + (size_t)PAIRS * MD;   // [65536]
constexpr size_t OFF_S2   = OFF_S1   + (size_t)PAIRS;        // [65536]
constexpr size_t OFF_X    = OFF_S2   + (size_t)PAIRS;        // [1024][256]
constexpr size_t OFF_GI   = OFF_X    + (size_t)ROWS * MD;    // [1024][768]
constexpr size_t OFF_GH   = OFF_GI   + (size_t)ROWS * 3 * MD;// [1024][768]
constexpr size_t OFF_HN   = OFF_GH   + (size_t)ROWS * 3 * MD;// [1024][256]

__device__ __forceinline__ float sigmoidf_(float x) { return 1.0f / (1.0f + expf(-x)); }

// ---------------------------------------------------------------------------
// Generic small tiled NT GEMM: C[M][N] = A[M][K] @ B[N][K]^T (+ bias[N])
// BM=32, BN=64, BK=16, 256 threads, 2x4 micro-tile.
// Requires M%32==0, K%4==0. N guarded.
// ---------------------------------------------------------------------------
__global__ __launch_bounds__(256) void small_gemm(
    const float* __restrict__ A, int lda,
    const float* __restrict__ Bm, int ldb,
    const float* __restrict__ bias,
    float* __restrict__ C, int ldc,
    int M, int N, int K, int gn)
{
  const int bm = blockIdx.x / gn;
  const int bn = blockIdx.x % gn;
  const int row0 = bm * 32;
  const int col0 = bn * 64;
  const int tid = threadIdx.x;
  const int tx = tid & 15;   // j = tx*4
  const int ty = tid >> 4;   // r = ty*2
  __shared__ float As[16][32];
  __shared__ float Bs[16][64];

  float acc[2][4] = {};
  const int nChunks = (K + 15) / 16;
  for (int ck = 0; ck < nChunks; ++ck) {
    const int k0 = ck * 16;
    __syncthreads();
    if (tid < 128) {                       // A: 32 rows x 16 k = 128 float4
      int rr = tid >> 2, kq = tid & 3;
      int k = k0 + kq * 4;
      float4 v = make_float4(0.f, 0.f, 0.f, 0.f);
      if (k + 4 <= K)
        v = *reinterpret_cast<const float4*>(&A[(size_t)(row0 + rr) * lda + k]);
      As[kq*4+0][rr] = v.x; As[kq*4+1][rr] = v.y;
      As[kq*4+2][rr] = v.z; As[kq*4+3][rr] = v.w;
    }
    {                                      // B: 64 rows x 16 k = 256 float4
      int jj = tid >> 2, kq = tid & 3;
      int k = k0 + kq * 4;
      float4 v = make_float4(0.f, 0.f, 0.f, 0.f);
      if ((col0 + jj) < N && k + 4 <= K)
        v = *reinterpret_cast<const float4*>(&Bm[(size_t)(col0 + jj) * ldb + k]);
      Bs[kq*4+0][jj] = v.x; Bs[kq*4+1][jj] = v.y;
      Bs[kq*4+2][jj] = v.z; Bs[kq*4+3][jj] = v.w;
    }
    __syncthreads();
#pragma unroll
    for (int k = 0; k < 16; ++k) {
      float a0 = As[k][ty*2], a1 = As[k][ty*2+1];
      float4 b = *reinterpret_cast<const float4*>(&Bs[k][tx*4]);
      acc[0][0] += a0*b.x; acc[0][1] += a0*b.y; acc[0][2] += a0*b.z; acc[0][3] += a0*b.w;
      acc[1][0] += a1*b.x; acc[1][1] += a1*b.y; acc[1][2] += a1*b.z; acc[1][3] += a1*b.w;
    }
  }
#pragma unroll
  for (int i = 0; i < 2; ++i) {
    int r = row0 + ty*2 + i;
#pragma unroll
    for (int j = 0; j < 4; ++j) {
      int c = col0 + tx*4 + j;
      if (c < N) {
        float v = acc[i][j];
        if (bias) v += bias[c];
        C[(size_t)r * ldc + c] = v;
      }
    }
  }
}

// ---------------------------------------------------------------------------
// 128x128-tile NT GEMM, BK=16, 256 threads, 8x8 micro-tile.
// Requires M%128==0, N%128==0, K%16==0.
// MODE 0: C = A@B^T + bias[N]
// MODE 1: C = relu(A@B^T + xph[(b*64+w)][c] + bias[c])   (row = b*4096+v*64+w)
// ---------------------------------------------------------------------------
template<int MODE>
__global__ __launch_bounds__(256) void gemm128(
    const float* __restrict__ A, int lda,
    const float* __restrict__ Bm, int ldb,
    const float* __restrict__ bias,
    const float* __restrict__ xph,
    float* __restrict__ C, int ldc,
    int M, int N, int K)
{
  const int gn = N >> 7;
  const int bm_ = blockIdx.x / gn;
  const int bn_ = blockIdx.x % gn;
  const int row0 = bm_ << 7, col0 = bn_ << 7;
  const int tid = threadIdx.x;
  const int tx = tid & 15, ty = tid >> 4;
  __shared__ float As[16][128];
  __shared__ float Bs[16][128];
  float acc[8][8] = {};

  for (int k0 = 0; k0 < K; k0 += 16) {
    __syncthreads();
#pragma unroll
    for (int l = 0; l < 2; ++l) {          // A tile: 512 float4
      int idx = l * 256 + tid;
      int rr = idx >> 2, kq = idx & 3;
      float4 v = *reinterpret_cast<const float4*>(&A[(size_t)(row0 + rr) * lda + k0 + kq*4]);
      As[kq*4+0][rr] = v.x; As[kq*4+1][rr] = v.y;
      As[kq*4+2][rr] = v.z; As[kq*4+3][rr] = v.w;
    }
#pragma unroll
    for (int l = 0; l < 2; ++l) {          // B tile: 512 float4
      int idx = l * 256 + tid;
      int jj = idx >> 2, kq = idx & 3;
      float4 v = *reinterpret_cast<const float4*>(&Bm[(size_t)(col0 + jj) * ldb + k0 + kq*4]);
      Bs[kq*4+0][jj] = v.x; Bs[kq*4+1][jj] = v.y;
      Bs[kq*4+2][jj] = v.z; Bs[kq*4+3][jj] = v.w;
    }
    __syncthreads();
#pragma unroll
    for (int k = 0; k < 16; ++k) {
      float4 a0 = *reinterpret_cast<const float4*>(&As[k][ty*8]);
      float4 a1 = *reinterpret_cast<const float4*>(&As[k][ty*8+4]);
      float4 b0 = *reinterpret_cast<const float4*>(&Bs[k][tx*8]);
      float4 b1 = *reinterpret_cast<const float4*>(&Bs[k][tx*8+4]);
      float av[8] = {a0.x,a0.y,a0.z,a0.w,a1.x,a1.y,a1.z,a1.w};
      float bv[8] = {b0.x,b0.y,b0.z,b0.w,b1.x,b1.y,b1.z,b1.w};
#pragma unroll
      for (int i = 0; i < 8; ++i)
#pragma unroll
        for (int j = 0; j < 8; ++j)
          acc[i][j] += av[i] * bv[j];
    }
  }

#pragma unroll
  for (int i = 0; i < 8; ++i) {
    int r = row0 + ty*8 + i;
    if (MODE == 0) {
#pragma unroll
      for (int j = 0; j < 8; ++j) {
        int c = col0 + tx*8 + j;
        C[(size_t)r * ldc + c] = acc[i][j] + bias[c];
      }
    } else {
      int rx = ((r >> 12) << 6) | (r & 63);  // b*64 + w
#pragma unroll
      for (int j = 0; j < 8; ++j) {
        int c = col0 + tx*8 + j;
        float v = acc[i][j] + xph[(size_t)rx * 256 + c] + bias[c];
        C[(size_t)r * ldc + c] = fmaxf(v, 0.0f);
      }
    }
  }
}

// ---------------------------------------------------------------------------
// Attention score pass: per block (b,v), 64 pairs (w) x 256 hidden, K=256.
//   h1 = relu(Wl1 @ rowvec + bl1);  A = Wl2 . h1 + bl2
// SECOND==0: rowvec = E0[b*4096+v*64+w];            out: S1 = sigmoid(A)
// SECOND==1: rowvec = Mpre[b*4096+w*64+v]*S1[same]; out: adj = A, S2 = sigmoid(A)
// ---------------------------------------------------------------------------
template<int SECOND>
__global__ __launch_bounds__(256) void attn_gemv(
    const float* __restrict__ Ain,
    const float* __restrict__ S1,
    const float* __restrict__ Wl1,
    const float* __restrict__ bl1,
    const float* __restrict__ Wl2,
    const float* __restrict__ bl2,
    float* __restrict__ outS,
    float* __restrict__ outA)
{
  const int b = blockIdx.x >> 6;
  const int v = blockIdx.x & 63;
  const int tid = threadIdx.x;
  const int tx = tid & 31, ty = tid >> 5;
  __shared__ float As[32][64];
  __shared__ float Bs[32][256];
  __shared__ float red[64][33];
  float acc[8][8] = {};

  for (int k0 = 0; k0 < 256; k0 += 32) {
    __syncthreads();
#pragma unroll
    for (int l = 0; l < 2; ++l) {          // A: 64 rows x 32 k = 512 float4
      int idx = l * 256 + tid;
      int rr = idx >> 3, kq = idx & 7;
      int pair = SECOND ? (b*4096 + rr*64 + v) : (b*4096 + v*64 + rr);
      float sc = 1.0f;
      if (SECOND) sc = S1[pair];
      float4 vv = *reinterpret_cast<const float4*>(&Ain[(size_t)pair * 256 + k0 + kq*4]);
      As[kq*4+0][rr] = vv.x * sc; As[kq*4+1][rr] = vv.y * sc;
      As[kq*4+2][rr] = vv.z * sc; As[kq*4+3][rr] = vv.w * sc;
    }
#pragma unroll
    for (int l = 0; l < 8; ++l) {          // B: 256 rows x 32 k = 2048 float4
      int idx = l * 256 + tid;
      int jj = idx >> 3, kq = idx & 7;
      float4 vv = *reinterpret_cast<const float4*>(&Wl1[(size_t)jj * 256 + k0 + kq*4]);
      Bs[kq*4+0][jj] = vv.x; Bs[kq*4+1][jj] = vv.y;
      Bs[kq*4+2][jj] = vv.z; Bs[kq*4+3][jj] = vv.w;
    }
    __syncthreads();
#pragma unroll
    for (int k = 0; k < 32; ++k) {
      float4 a0 = *reinterpret_cast<const float4*>(&As[k][ty*8]);
      float4 a1 = *reinterpret_cast<const float4*>(&As[k][ty*8+4]);
      float4 b0 = *reinterpret_cast<const float4*>(&Bs[k][tx*8]);
      float4 b1 = *reinterpret_cast<const float4*>(&Bs[k][tx*8+4]);
      float av[8] = {a0.x,a0.y,a0.z,a0.w,a1.x,a1.y,a1.z,a1.w};
      float bv[8] = {b0.x,b0.y,b0.z,b0.w,b1.x,b1.y,b1.z,b1.w};
#pragma unroll
      for (int p = 0; p < 8; ++p)
#pragma unroll
        for (int j = 0; j < 8; ++j)
          acc[p][j] += av[p] * bv[j];
    }
  }

#pragma unroll
  for (int p = 0; p < 8; ++p) {
    int w = ty*8 + p;
    float part = 0.f;
#pragma unroll
    for (int j = 0; j < 8; ++j) {
      int c = tx*8 + j;
      float h = fmaxf(acc[p][j] + bl1[c], 0.0f);
      part += Wl2[c] * h;
    }
    red[w][tx] = part;
  }
  __syncthreads();
  if (tid < 64) {
    int w = tid;
    float s = bl2[0];
#pragma unroll
    for (int t = 0; t < 32; ++t) s += red[w][t];
    int out_idx = b*4096 + v*64 + w;
    if (SECOND) {
      outA[out_idx] = s;
      outS[out_idx] = sigmoidf_(s);
    } else {
      outS[out_idx] = sigmoidf_(s);
    }
  }
}

// x[bv][c] = sum_w Mpre[bv*64+w][c] * S2[bv*64+w]
__global__ __launch_bounds__(256) void msum_kernel(
    const float* __restrict__ Mpre, const float* __restrict__ S2,
    float* __restrict__ x)
{
  const int bv = blockIdx.x;
  const int c = threadIdx.x;
  float acc = 0.f;
#pragma unroll 4
  for (int w = 0; w < 64; ++w)
    acc += Mpre[((size_t)bv * 64 + w) * 256 + c] * S2[bv * 64 + w];
  x[(size_t)bv * 256 + c] = acc;
}

__global__ __launch_bounds__(256) void gru_kernel(
    const float* __restrict__ gi, const float* __restrict__ gh,
    const float* __restrict__ Xp, float* __restrict__ hn)
{
  const int row = blockIdx.x, c = threadIdx.x;
  const float* gir = gi + (size_t)row * 768;
  const float* ghr = gh + (size_t)row * 768;
  float r = sigmoidf_(gir[c] + ghr[c]);
  float z = sigmoidf_(gir[256 + c] + ghr[256 + c]);
  float n = tanhf(gir[512 + c] + r * ghr[512 + c]);
  float h = Xp[(size_t)row * 256 + c];
  hn[(size_t)row * 256 + c] = (1.0f - z) * n + z * h;
}

} // namespace

extern "C" void kernel_launch(void* const* d_in, const int* in_sizes, int n_in,
                              void* d_out, int out_size, void* d_ws, size_t ws_size,
                              hipStream_t stream)
{
  const float* ef   = (const float*)d_in[0];
  const float* nf   = (const float*)d_in[1];
  const float* W_er = (const float*)d_in[7];
  const float* b_er = (const float*)d_in[8];
  const float* W_nr = (const float*)d_in[9];
  const float* b_nr = (const float*)d_in[10];
  const float* Wl1  = (const float*)d_in[11];
  const float* bl1  = (const float*)d_in[12];
  const float* Wl2  = (const float*)d_in[13];
  const float* bl2  = (const float*)d_in[14];
  const float* Wm   = (const float*)d_in[15];
  const float* bm   = (const float*)d_in[16];
  const float* Wi   = (const float*)d_in[17];
  const float* bi   = (const float*)d_in[18];
  const float* Wh   = (const float*)d_in[19];
  const float* bh   = (const float*)d_in[20];
  const float* Wro  = (const float*)d_in[21];
  const float* bro  = (const float*)d_in[22];

  float* ws   = (float*)d_ws;
  float* Xp   = ws + OFF_XP;
  float* XpH  = ws + OFF_XPH;
  float* E0   = ws + OFF_E0;
  float* Mpre = ws + OFF_MPRE;
  float* S1   = ws + OFF_S1;
  float* S2   = ws + OFF_S2;
  float* xbuf = ws + OFF_X;
  float* gi   = ws + OFF_GI;
  float* gh   = ws + OFF_GH;
  float* hn   = ws + OFF_HN;
  float* adj    = (float*)d_out;           // [16][64][64]
  float* labels = (float*)d_out + PAIRS;   // [16][64][600]

  dim3 blk(256);

  // Xp_t[b*64+v][m] = nf[b,v,:] . W_nr[m,:] + b_nr[m]
  small_gemm<<<dim3(32 * 4), blk, 0, stream>>>(nf, FN, W_nr, FN, b_nr, Xp, MD,
                                               ROWS, MD, FN, 4);
  // XpH_t[b*64+w][c] = Xp_t[b*64+w,:] . W_hw[c,:]   (W_hw = Wm[:, :256], ldb=512)
  small_gemm<<<dim3(32 * 4), blk, 0, stream>>>(Xp, MD, Wm, 2 * MD, nullptr, XpH, MD,
                                               ROWS, MD, MD, 4);
  // E0[pair][c] = ef[pair,:] . W_er[c,:] + b_er[c]
  gemm128<0><<<dim3(512 * 2), blk, 0, stream>>>(ef, FE, W_er, FE, b_er, nullptr,
                                                E0, MD, PAIRS, MD, FE);
  // S1 (iteration 1 scores)
  attn_gemv<0><<<dim3(1024), blk, 0, stream>>>(E0, nullptr, Wl1, bl1, Wl2, bl2,
                                               S1, nullptr);
  // Mpre[pair][c] = relu(E0[pair,:].W_ev[c,:] + XpH[b*64+w][c] + bm[c])
  gemm128<1><<<dim3(512 * 2), blk, 0, stream>>>(E0, MD, Wm + MD, 2 * MD, bm, XpH,
                                                Mpre, MD, PAIRS, MD, MD);
  // iteration 2 scores: adj = A2, S2 = sigmoid(A2)
  attn_gemv<1><<<dim3(1024), blk, 0, stream>>>(Mpre, S1, Wl1, bl1, Wl2, bl2,
                                               S2, adj);
  // x[bv][c] = sum_w Mpre * S2
  msum_kernel<<<dim3(1024), blk, 0, stream>>>(Mpre, S2, xbuf);
  // gi = x @ Wi^T + bi ; gh = Xp @ Wh^T + bh
  small_gemm<<<dim3(32 * 12), blk, 0, stream>>>(xbuf, MD, Wi, MD, bi, gi, 3 * MD,
                                                ROWS, 3 * MD, MD, 12);
  small_gemm<<<dim3(32 * 12), blk, 0, stream>>>(Xp, MD, Wh, MD, bh, gh, 3 * MD,
                                                ROWS, 3 * MD, MD, 12);
  // GRU
  gru_kernel<<<dim3(1024), blk, 0, stream>>>(gi, gh, Xp, hn);
  // labels = h_new @ Wro^T + bro
  small_gemm<<<dim3(32 * 10), blk, 0, stream>>>(hn, MD, Wro, MD, bro, labels, KC,
                                                ROWS, KC, MD, 10);
}

// Round 2
// 384.322 us; speedup vs baseline: 2.6479x; 2.6479x over previous
//
#include <hip/hip_runtime.h>
#include <cmath>

namespace {

using f16 = _Float16;
typedef f16 f16x8 __attribute__((ext_vector_type(8)));
typedef float f32x4 __attribute__((ext_vector_type(4)));

constexpr int FE = 1216, FN = 1108, MD = 256, KC = 600;
constexpr int PAIRS = 65536, ROWS = 1024;

// workspace offsets (float units; all multiples of 4 -> 16B aligned)
constexpr size_t OFF_XP    = 0;
constexpr size_t OFF_XPH   = OFF_XP    + (size_t)ROWS * MD;
constexpr size_t OFF_X     = OFF_XPH   + (size_t)ROWS * MD;
constexpr size_t OFF_GI    = OFF_X     + (size_t)ROWS * MD;
constexpr size_t OFF_GH    = OFF_GI    + (size_t)ROWS * 3 * MD;
constexpr size_t OFF_HN    = OFF_GH    + (size_t)ROWS * 3 * MD;
constexpr size_t OFF_S1    = OFF_HN    + (size_t)ROWS * MD;
constexpr size_t OFF_S2    = OFF_S1    + PAIRS;
constexpr size_t OFF_WER8  = OFF_S2    + PAIRS;                    // 1216*256 f16
constexpr size_t OFF_WEV8  = OFF_WER8  + (size_t)FE * MD / 2;      // 256*256 f16
constexpr size_t OFF_WL18  = OFF_WEV8  + (size_t)MD * MD / 2;      // 256*256 f16
constexpr size_t OFF_E0H   = OFF_WL18  + (size_t)MD * MD / 2;      // 65536*256 f16
constexpr size_t OFF_MPREH = OFF_E0H   + (size_t)PAIRS * MD / 2;   // 65536*256 f16

__device__ __forceinline__ float sigmoidf_(float x) { return 1.0f / (1.0f + expf(-x)); }

// ---------------------------------------------------------------------------
// Pre-fragment a weight matrix W[n][koff + k] (fp32, ld=ldw) into f16 layout
// out[(kc*256 + n)*8 + j] = W[n][koff + kc*8 + j]; one block per kc, thread=n.
// ---------------------------------------------------------------------------
__global__ __launch_bounds__(256) void cast_prefrag(
    const float* __restrict__ W, int ldw, int koff, f16* __restrict__ out)
{
  const int kc = blockIdx.x, n = threadIdx.x;
  const float* src = W + (size_t)n * ldw + koff + kc * 8;
  f16x8 h;
#pragma unroll
  for (int j = 0; j < 8; ++j) h[j] = (f16)src[j];
  *reinterpret_cast<f16x8*>(out + ((size_t)kc * 256 + n) * 8) = h;
}

// ---------------------------------------------------------------------------
// E0 GEMM: M=65536, N=256, K=1216.  A = ef (fp32), B = W_er prefrag f16.
// Block: 256 thr = 4 waves; BM=64, BN=256 (full), BK=64. Out: E0 f16 (+bias).
// ---------------------------------------------------------------------------
__global__ __launch_bounds__(256) void gemm_e0(
    const float* __restrict__ A, const f16* __restrict__ Bp,
    const float* __restrict__ bias, f16* __restrict__ C)
{
  const int blk = blockIdx.x;              // 1024
  const int tid = threadIdx.x;
  const int wave = tid >> 6, l = tid & 63;
  const int lo = l & 15, hi = l >> 4;
  const int wcol = wave * 64;
  __shared__ f16 As[64][72];               // pad 64 -> 72 (144B row stride)
  f32x4 acc[4][4] = {};
  const size_t arow0 = (size_t)blk * 64;
  const int srow = tid >> 2, spart = tid & 3;        // staging: 4 thr/row
  const float* aptr = A + (arow0 + srow) * FE + spart * 16;

  for (int k0 = 0; k0 < FE; k0 += 64) {
    __syncthreads();
    float4 v0 = *reinterpret_cast<const float4*>(aptr + 0);
    float4 v1 = *reinterpret_cast<const float4*>(aptr + 4);
    float4 v2 = *reinterpret_cast<const float4*>(aptr + 8);
    float4 v3 = *reinterpret_cast<const float4*>(aptr + 12);
    f16x8 h0, h1;
    h0[0]=(f16)v0.x; h0[1]=(f16)v0.y; h0[2]=(f16)v0.z; h0[3]=(f16)v0.w;
    h0[4]=(f16)v1.x; h0[5]=(f16)v1.y; h0[6]=(f16)v1.z; h0[7]=(f16)v1.w;
    h1[0]=(f16)v2.x; h1[1]=(f16)v2.y; h1[2]=(f16)v2.z; h1[3]=(f16)v2.w;
    h1[4]=(f16)v3.x; h1[5]=(f16)v3.y; h1[6]=(f16)v3.z; h1[7]=(f16)v3.w;
    *reinterpret_cast<f16x8*>(&As[srow][spart*16])     = h0;
    *reinterpret_cast<f16x8*>(&As[srow][spart*16 + 8]) = h1;
    aptr += 64;
    __syncthreads();
#pragma unroll
    for (int ks = 0; ks < 2; ++ks) {
      f16x8 af[4], bf[4];
      const int kc = (k0 >> 3) + ks * 4 + hi;
#pragma unroll
      for (int m = 0; m < 4; ++m)
        af[m] = *reinterpret_cast<const f16x8*>(&As[m*16 + lo][ks*32 + hi*8]);
#pragma unroll
      for (int n = 0; n < 4; ++n)
        bf[n] = *reinterpret_cast<const f16x8*>(Bp + ((size_t)kc*256 + (wcol + n*16 + lo)) * 8);
#pragma unroll
      for (int m = 0; m < 4; ++m)
#pragma unroll
        for (int n = 0; n < 4; ++n)
          acc[m][n] = __builtin_amdgcn_mfma_f32_16x16x32_f16(af[m], bf[n], acc[m][n], 0, 0, 0);
    }
  }
#pragma unroll
  for (int m = 0; m < 4; ++m)
#pragma unroll
    for (int n = 0; n < 4; ++n) {
      const int col = wcol + n*16 + lo;
      const float bb = bias[col];
#pragma unroll
      for (int r = 0; r < 4; ++r) {
        const size_t row = arow0 + m*16 + hi*4 + r;
        C[row * 256 + col] = (f16)(acc[m][n][r] + bb);
      }
    }
}

// ---------------------------------------------------------------------------
// Mpre GEMM: M=65536, N=256, K=256. A = E0 f16, B = W_ev prefrag.
// Epilogue: relu(acc + XpH[b*64+w][c] + bm[c]) -> f16.
// ---------------------------------------------------------------------------
__global__ __launch_bounds__(256) void gemm_mpre(
    const f16* __restrict__ Ain, const f16* __restrict__ Bp,
    const float* __restrict__ XpH, const float* __restrict__ bm,
    f16* __restrict__ C)
{
  const int blk = blockIdx.x;
  const int tid = threadIdx.x;
  const int wave = tid >> 6, l = tid & 63;
  const int lo = l & 15, hi = l >> 4;
  const int wcol = wave * 64;
  __shared__ f16 As[64][72];
  f32x4 acc[4][4] = {};

  for (int k0 = 0; k0 < 256; k0 += 64) {
    __syncthreads();
#pragma unroll
    for (int i = 0; i < 2; ++i) {
      int idx = i * 256 + tid;
      int rr = idx >> 3, part = idx & 7;
      f16x8 h = *reinterpret_cast<const f16x8*>(Ain + ((size_t)blk*64 + rr)*256 + k0 + part*8);
      *reinterpret_cast<f16x8*>(&As[rr][part*8]) = h;
    }
    __syncthreads();
#pragma unroll
    for (int ks = 0; ks < 2; ++ks) {
      f16x8 af[4], bf[4];
      const int kc = (k0 >> 3) + ks * 4 + hi;
#pragma unroll
      for (int m = 0; m < 4; ++m)
        af[m] = *reinterpret_cast<const f16x8*>(&As[m*16 + lo][ks*32 + hi*8]);
#pragma unroll
      for (int n = 0; n < 4; ++n)
        bf[n] = *reinterpret_cast<const f16x8*>(Bp + ((size_t)kc*256 + (wcol + n*16 + lo)) * 8);
#pragma unroll
      for (int m = 0; m < 4; ++m)
#pragma unroll
        for (int n = 0; n < 4; ++n)
          acc[m][n] = __builtin_amdgcn_mfma_f32_16x16x32_f16(af[m], bf[n], acc[m][n], 0, 0, 0);
    }
  }
  const int rxb = (blk >> 6) * 64;         // b*64 (+ w = local row)
#pragma unroll
  for (int m = 0; m < 4; ++m)
#pragma unroll
    for (int n = 0; n < 4; ++n) {
      const int col = wcol + n*16 + lo;
      const float bb = bm[col];
#pragma unroll
      for (int r = 0; r < 4; ++r) {
        const int rl = m*16 + hi*4 + r;
        float v = acc[m][n][r] + XpH[(size_t)(rxb + rl)*256 + col] + bb;
        C[((size_t)blk*64 + rl)*256 + col] = (f16)fmaxf(v, 0.0f);
      }
    }
}

// ---------------------------------------------------------------------------
// Attention score pass (MFMA): per block 64 rows x 256 hidden, K=256.
// SECOND==0: A-row = E0[blk*64+rr];               out: S1 = sigmoid(A)
// SECOND==1: A-row = Mpre[b*4096+rr*64+v]*S1[.];  out: adj = A, S2 = sigmoid(A)
// ---------------------------------------------------------------------------
template<int SECOND>
__global__ __launch_bounds__(256) void attn_mfma(
    const f16* __restrict__ Ain, const float* __restrict__ S1,
    const f16* __restrict__ Bp,  const float* __restrict__ bl1,
    const float* __restrict__ Wl2, const float* __restrict__ bl2,
    float* __restrict__ outS, float* __restrict__ outA)
{
  const int blk = blockIdx.x;
  const int b = blk >> 6, v = blk & 63;
  const int tid = threadIdx.x;
  const int wave = tid >> 6, l = tid & 63;
  const int lo = l & 15, hi = l >> 4;
  const int wcol = wave * 64;
  __shared__ f16 As[64][72];
  __shared__ float red[64][4];
  f32x4 acc[4][4] = {};

  for (int k0 = 0; k0 < 256; k0 += 64) {
    __syncthreads();
#pragma unroll
    for (int i = 0; i < 2; ++i) {
      int idx = i * 256 + tid;
      int rr = idx >> 3, part = idx & 7;
      size_t pair = SECOND ? ((size_t)b*4096 + rr*64 + v) : ((size_t)blk*64 + rr);
      f16x8 h = *reinterpret_cast<const f16x8*>(Ain + pair*256 + k0 + part*8);
      if (SECOND) {
        float sc = S1[pair];
#pragma unroll
        for (int j = 0; j < 8; ++j) h[j] = (f16)((float)h[j] * sc);
      }
      *reinterpret_cast<f16x8*>(&As[rr][part*8]) = h;
    }
    __syncthreads();
#pragma unroll
    for (int ks = 0; ks < 2; ++ks) {
      f16x8 af[4], bf[4];
      const int kc = (k0 >> 3) + ks * 4 + hi;
#pragma unroll
      for (int m = 0; m < 4; ++m)
        af[m] = *reinterpret_cast<const f16x8*>(&As[m*16 + lo][ks*32 + hi*8]);
#pragma unroll
      for (int n = 0; n < 4; ++n)
        bf[n] = *reinterpret_cast<const f16x8*>(Bp + ((size_t)kc*256 + (wcol + n*16 + lo)) * 8);
#pragma unroll
      for (int m = 0; m < 4; ++m)
#pragma unroll
        for (int n = 0; n < 4; ++n)
          acc[m][n] = __builtin_amdgcn_mfma_f32_16x16x32_f16(af[m], bf[n], acc[m][n], 0, 0, 0);
    }
  }
  // per-row: sum_c Wl2[c] * relu(acc + bl1[c]); reduce 16 lanes (lo) + 4 waves
#pragma unroll
  for (int m = 0; m < 4; ++m) {
#pragma unroll
    for (int r = 0; r < 4; ++r) {
      float p = 0.f;
#pragma unroll
      for (int n = 0; n < 4; ++n) {
        const int col = wcol + n*16 + lo;
        p += Wl2[col] * fmaxf(acc[m][n][r] + bl1[col], 0.0f);
      }
      p += __shfl_xor(p, 1);
      p += __shfl_xor(p, 2);
      p += __shfl_xor(p, 4);
      p += __shfl_xor(p, 8);
      if (lo == 0) red[m*16 + hi*4 + r][wave] = p;
    }
  }
  __syncthreads();
  if (tid < 64) {
    float s = bl2[0] + red[tid][0] + red[tid][1] + red[tid][2] + red[tid][3];
    size_t out_idx = SECOND ? ((size_t)b*4096 + v*64 + tid) : ((size_t)blk*64 + tid);
    if (SECOND) { outA[out_idx] = s; outS[out_idx] = sigmoidf_(s); }
    else        { outS[out_idx] = sigmoidf_(s); }
  }
}

// x[bv][c] = sum_w Mpre[bv*64+w][c] * S2[bv*64+w]
__global__ __launch_bounds__(256) void msum_kernel(
    const f16* __restrict__ Mpre, const float* __restrict__ S2,
    float* __restrict__ x)
{
  const int bv = blockIdx.x;
  const int c = threadIdx.x;
  float acc = 0.f;
#pragma unroll 4
  for (int w = 0; w < 64; ++w)
    acc += (float)Mpre[((size_t)bv * 64 + w) * 256 + c] * S2[bv * 64 + w];
  x[(size_t)bv * 256 + c] = acc;
}

// ---------------------------------------------------------------------------
// Generic small tiled NT GEMM (fp32): C[M][N] = A[M][K] @ B[N][K]^T (+ bias)
// ---------------------------------------------------------------------------
__global__ __launch_bounds__(256) void small_gemm(
    const float* __restrict__ A, int lda,
    const float* __restrict__ Bm, int ldb,
    const float* __restrict__ bias,
    float* __restrict__ C, int ldc,
    int M, int N, int K, int gn)
{
  const int bm = blockIdx.x / gn;
  const int bn = blockIdx.x % gn;
  const int row0 = bm * 32;
  const int col0 = bn * 64;
  const int tid = threadIdx.x;
  const int tx = tid & 15;
  const int ty = tid >> 4;
  __shared__ float As[16][32];
  __shared__ float Bs[16][64];

  float acc[2][4] = {};
  const int nChunks = (K + 15) / 16;
  for (int ck = 0; ck < nChunks; ++ck) {
    const int k0 = ck * 16;
    __syncthreads();
    if (tid < 128) {
      int rr = tid >> 2, kq = tid & 3;
      int k = k0 + kq * 4;
      float4 v = make_float4(0.f, 0.f, 0.f, 0.f);
      if (k + 4 <= K)
        v = *reinterpret_cast<const float4*>(&A[(size_t)(row0 + rr) * lda + k]);
      As[kq*4+0][rr] = v.x; As[kq*4+1][rr] = v.y;
      As[kq*4+2][rr] = v.z; As[kq*4+3][rr] = v.w;
    }
    {
      int jj = tid >> 2, kq = tid & 3;
      int k = k0 + kq * 4;
      float4 v = make_float4(0.f, 0.f, 0.f, 0.f);
      if ((col0 + jj) < N && k + 4 <= K)
        v = *reinterpret_cast<const float4*>(&Bm[(size_t)(col0 + jj) * ldb + k]);
      Bs[kq*4+0][jj] = v.x; Bs[kq*4+1][jj] = v.y;
      Bs[kq*4+2][jj] = v.z; Bs[kq*4+3][jj] = v.w;
    }
    __syncthreads();
#pragma unroll
    for (int k = 0; k < 16; ++k) {
      float a0 = As[k][ty*2], a1 = As[k][ty*2+1];
      float4 bq = *reinterpret_cast<const float4*>(&Bs[k][tx*4]);
      acc[0][0] += a0*bq.x; acc[0][1] += a0*bq.y; acc[0][2] += a0*bq.z; acc[0][3] += a0*bq.w;
      acc[1][0] += a1*bq.x; acc[1][1] += a1*bq.y; acc[1][2] += a1*bq.z; acc[1][3] += a1*bq.w;
    }
  }
#pragma unroll
  for (int i = 0; i < 2; ++i) {
    int r = row0 + ty*2 + i;
#pragma unroll
    for (int j = 0; j < 4; ++j) {
      int c = col0 + tx*4 + j;
      if (c < N) {
        float v = acc[i][j];
        if (bias) v += bias[c];
        C[(size_t)r * ldc + c] = v;
      }
    }
  }
}

__global__ __launch_bounds__(256) void gru_kernel(
    const float* __restrict__ gi, const float* __restrict__ gh,
    const float* __restrict__ Xp, float* __restrict__ hn)
{
  const int row = blockIdx.x, c = threadIdx.x;
  const float* gir = gi + (size_t)row * 768;
  const float* ghr = gh + (size_t)row * 768;
  float r = sigmoidf_(gir[c] + ghr[c]);
  float z = sigmoidf_(gir[256 + c] + ghr[256 + c]);
  float n = tanhf(gir[512 + c] + r * ghr[512 + c]);
  float h = Xp[(size_t)row * 256 + c];
  hn[(size_t)row * 256 + c] = (1.0f - z) * n + z * h;
}

} // namespace

extern "C" void kernel_launch(void* const* d_in, const int* in_sizes, int n_in,
                              void* d_out, int out_size, void* d_ws, size_t ws_size,
                              hipStream_t stream)
{
  const float* ef   = (const float*)d_in[0];
  const float* nf   = (const float*)d_in[1];
  const float* W_er = (const float*)d_in[7];
  const float* b_er = (const float*)d_in[8];
  const float* W_nr = (const float*)d_in[9];
  const float* b_nr = (const float*)d_in[10];
  const float* Wl1  = (const float*)d_in[11];
  const float* bl1  = (const float*)d_in[12];
  const float* Wl2  = (const float*)d_in[13];
  const float* bl2  = (const float*)d_in[14];
  const float* Wm   = (const float*)d_in[15];
  const float* bm   = (const float*)d_in[16];
  const float* Wi   = (const float*)d_in[17];
  const float* bi   = (const float*)d_in[18];
  const float* Wh   = (const float*)d_in[19];
  const float* bh   = (const float*)d_in[20];
  const float* Wro  = (const float*)d_in[21];
  const float* bro  = (const float*)d_in[22];

  float* ws   = (float*)d_ws;
  float* Xp   = ws + OFF_XP;
  float* XpH  = ws + OFF_XPH;
  float* xbuf = ws + OFF_X;
  float* gi   = ws + OFF_GI;
  float* gh   = ws + OFF_GH;
  float* hn   = ws + OFF_HN;
  float* S1   = ws + OFF_S1;
  float* S2   = ws + OFF_S2;
  f16* Wer8   = (f16*)(ws + OFF_WER8);
  f16* Wev8   = (f16*)(ws + OFF_WEV8);
  f16* Wl18   = (f16*)(ws + OFF_WL18);
  f16* E0h    = (f16*)(ws + OFF_E0H);
  f16* Mpreh  = (f16*)(ws + OFF_MPREH);
  float* adj    = (float*)d_out;           // [16][64][64]
  float* labels = (float*)d_out + PAIRS;   // [16][64][600]

  dim3 blk(256);

  // weight prefrag casts (tiny)
  cast_prefrag<<<dim3(FE / 8), blk, 0, stream>>>(W_er, FE, 0, Wer8);
  cast_prefrag<<<dim3(MD / 8), blk, 0, stream>>>(Wm, 2 * MD, MD, Wev8);  // W_ev = Wm[:,256:]
  cast_prefrag<<<dim3(MD / 8), blk, 0, stream>>>(Wl1, MD, 0, Wl18);

  // Xp[b*64+v][m] = nf . W_nr^T + b_nr   (fp32)
  small_gemm<<<dim3(32 * 4), blk, 0, stream>>>(nf, FN, W_nr, FN, b_nr, Xp, MD,
                                               ROWS, MD, FN, 4);
  // XpH[b*64+w][c] = Xp . W_hw^T   (W_hw = Wm[:, :256], ld = 512)
  small_gemm<<<dim3(32 * 4), blk, 0, stream>>>(Xp, MD, Wm, 2 * MD, nullptr, XpH, MD,
                                               ROWS, MD, MD, 4);
  // E0 (f16 MFMA): ef @ W_er^T + b_er -> f16
  gemm_e0<<<dim3(PAIRS / 64), blk, 0, stream>>>(ef, Wer8, b_er, E0h);
  // iteration-1 scores
  attn_mfma<0><<<dim3(PAIRS / 64), blk, 0, stream>>>(E0h, nullptr, Wl18, bl1, Wl2, bl2,
                                                     S1, nullptr);
  // Mpre = relu(E0 @ W_ev^T + XpH + bm) -> f16
  gemm_mpre<<<dim3(PAIRS / 64), blk, 0, stream>>>(E0h, Wev8, XpH, bm, Mpreh);
  // iteration-2 scores: adj = A2, S2 = sigmoid(A2)
  attn_mfma<1><<<dim3(PAIRS / 64), blk, 0, stream>>>(Mpreh, S1, Wl18, bl1, Wl2, bl2,
                                                     S2, adj);
  // x[bv][c] = sum_w Mpre * S2
  msum_kernel<<<dim3(ROWS), blk, 0, stream>>>(Mpreh, S2, xbuf);
  // GRU gates (fp32)
  small_gemm<<<dim3(32 * 12), blk, 0, stream>>>(xbuf, MD, Wi, MD, bi, gi, 3 * MD,
                                                ROWS, 3 * MD, MD, 12);
  small_gemm<<<dim3(32 * 12), blk, 0, stream>>>(Xp, MD, Wh, MD, bh, gh, 3 * MD,
                                                ROWS, 3 * MD, MD, 12);
  gru_kernel<<<dim3(ROWS), blk, 0, stream>>>(gi, gh, Xp, hn);
  // labels = h_new @ Wro^T + bro
  small_gemm<<<dim3(32 * 10), blk, 0, stream>>>(hn, MD, Wro, MD, bro, labels, KC,
                                                ROWS, KC, MD, 10);
}